// Round 1
// baseline (375.444 us; speedup 1.0000x reference)
//
#include <hip/hip_runtime.h>

#define EPS 1e-8f
#define BM 128
#define BN 128
#define BK 32

typedef __attribute__((ext_vector_type(8))) short bf16x8;   // 8 bf16 = 4 VGPRs
typedef __attribute__((ext_vector_type(4))) float f32x4;    // MFMA C/D

// RNE float -> bf16 (inputs are finite normals; no NaN handling needed)
__device__ inline unsigned short f2bf(float f) {
    union { float f; unsigned u; } c; c.f = f;
    unsigned u = c.u;
    return (unsigned short)((u + 0x7fffu + ((u >> 16) & 1u)) >> 16);
}

// One wave per row: norms + bf16 conversion. K must be a multiple of 4.
__global__ void prep_kernel(const float* __restrict__ x, unsigned short* __restrict__ xbf,
                            float* __restrict__ norms, int rows, int K) {
    const int row = blockIdx.x * 4 + (threadIdx.x >> 6);
    const int lane = threadIdx.x & 63;
    if (row >= rows) return;
    const float* p = x + (size_t)row * K;
    unsigned short* q = xbf + (size_t)row * K;
    float ss = 0.f;
    for (int base = lane * 4; base < K; base += 256) {
        float4 v = *(const float4*)(p + base);
        ss += v.x * v.x + v.y * v.y + v.z * v.z + v.w * v.w;
        ushort4 o;
        o.x = f2bf(v.x); o.y = f2bf(v.y); o.z = f2bf(v.z); o.w = f2bf(v.w);
        *(ushort4*)(q + base) = o;
    }
#pragma unroll
    for (int off = 32; off > 0; off >>= 1) ss += __shfl_down(ss, off, 64);
    if (lane == 0) norms[row] = sqrtf(ss);
}

#define GLOAD_LDS16(g, l)                                                         \
    __builtin_amdgcn_global_load_lds(                                             \
        (const __attribute__((address_space(1))) unsigned int*)(g),               \
        (__attribute__((address_space(3))) unsigned int*)(l), 16, 0, 0)

// C[m,n] = A[m,:]·B[n,:] / max(nA[m]*nB[n], eps). A=[M][K] bf16, B=[N][K] bf16.
__global__ __launch_bounds__(256) void gemm_cos_kernel(
    const unsigned short* __restrict__ A, const unsigned short* __restrict__ B,
    const float* __restrict__ nA, const float* __restrict__ nB,
    float* __restrict__ C, int M, int N, int K) {
    __shared__ unsigned short As[BM * BK];
    __shared__ unsigned short Bs[BN * BK];

    const int tid = threadIdx.x;
    const int wave = tid >> 6;
    const int lane = tid & 63;
    const int wm = wave >> 1;      // 2x2 wave grid over the 128x128 tile
    const int wn = wave & 1;
    const int quad = lane >> 4;
    const int l16 = lane & 15;

    const int row0 = blockIdx.y * BM;
    const int col0 = blockIdx.x * BN;

    // Staging: each lane fetches 16B (8 bf16) of its row; 16 rows / instr / wave.
    const int srow = lane >> 2;         // 0..15
    const int skcol = (lane & 3) * 8;   // 0,8,16,24

    const unsigned short* gA = A + (size_t)(row0 + wave * 32 + srow) * K + skcol;
    const unsigned short* gB = B + (size_t)(col0 + wave * 32 + srow) * K + skcol;
    unsigned short* lA = As + (wave * 32) * BK;   // wave-uniform LDS base
    unsigned short* lB = Bs + (wave * 32) * BK;

    f32x4 acc[4][4] = {};

    for (int kk = 0; kk < K; kk += BK) {
        GLOAD_LDS16(gA, lA);
        GLOAD_LDS16(gA + 16 * (size_t)K, lA + 16 * BK);
        GLOAD_LDS16(gB, lB);
        GLOAD_LDS16(gB + 16 * (size_t)K, lB + 16 * BK);
        gA += BK; gB += BK;
        __syncthreads();   // drains vmcnt: LDS tiles complete

        bf16x8 af[4], bfr[4];
#pragma unroll
        for (int mi = 0; mi < 4; mi++)
            af[mi] = *(const bf16x8*)(As + (wm * 64 + mi * 16 + l16) * BK + quad * 8);
#pragma unroll
        for (int ni = 0; ni < 4; ni++)
            bfr[ni] = *(const bf16x8*)(Bs + (wn * 64 + ni * 16 + l16) * BK + quad * 8);
#pragma unroll
        for (int mi = 0; mi < 4; mi++)
#pragma unroll
            for (int ni = 0; ni < 4; ni++)
                acc[mi][ni] = __builtin_amdgcn_mfma_f32_16x16x32_bf16(
                    af[mi], bfr[ni], acc[mi][ni], 0, 0, 0);
        __syncthreads();   // all waves done reading before next stage overwrites
    }

    // Epilogue: D[row=quad*4+r][col=l16] per 16x16 tile (m89/m91-verified layout)
    const int crow_base = row0 + wm * 64 + quad * 4;
    const int ccol_base = col0 + wn * 64 + l16;

    float rb[4];
#pragma unroll
    for (int ni = 0; ni < 4; ni++) rb[ni] = nB[ccol_base + ni * 16];

#pragma unroll
    for (int mi = 0; mi < 4; mi++) {
#pragma unroll
        for (int r = 0; r < 4; r++) {
            const int row = crow_base + mi * 16 + r;
            const float ra = nA[row];
            float* outp = C + (size_t)row * N + ccol_base;
#pragma unroll
            for (int ni = 0; ni < 4; ni++) {
                outp[ni * 16] = acc[mi][ni][r] / fmaxf(ra * rb[ni], EPS);
            }
        }
    }
}

// Correctness-guard fallback (weird shapes / tiny ws): naive fp32.
__global__ void naive_kernel(const float* __restrict__ x1, const float* __restrict__ x2,
                             float* __restrict__ out, int N, int M, int K) {
    long long idx = (long long)blockIdx.x * blockDim.x + threadIdx.x;
    if (idx >= (long long)M * N) return;
    int m = (int)(idx / N), n = (int)(idx % N);
    const float* a = x2 + (size_t)m * K;
    const float* b = x1 + (size_t)n * K;
    float dot = 0.f, sa = 0.f, sb = 0.f;
    for (int k = 0; k < K; k++) {
        float av = a[k], bv = b[k];
        dot += av * bv; sa += av * av; sb += bv * bv;
    }
    out[idx] = dot / fmaxf(sqrtf(sa) * sqrtf(sb), EPS);
}

extern "C" void kernel_launch(void* const* d_in, const int* in_sizes, int n_in,
                              void* d_out, int out_size, void* d_ws, size_t ws_size,
                              hipStream_t stream) {
    const float* x1 = (const float*)d_in[0];   // [N][K]
    const float* x2 = (const float*)d_in[1];   // [M][K]
    float* out = (float*)d_out;                // [M][N]
    const int K = 512;
    const int N = in_sizes[0] / K;
    const int M = in_sizes[1] / K;

    const size_t szA = (size_t)M * K * sizeof(unsigned short);
    const size_t szB = (size_t)N * K * sizeof(unsigned short);
    const size_t need = szA + szB + (size_t)(M + N) * sizeof(float);

    const bool fast = (in_sizes[0] % K == 0) && (in_sizes[1] % K == 0) &&
                      (M % BM == 0) && (N % BN == 0) && (K % BK == 0) &&
                      (need <= ws_size) && ((long long)M * N == (long long)out_size);

    if (fast) {
        unsigned short* Abf = (unsigned short*)d_ws;                       // x2 bf16
        unsigned short* Bbf = (unsigned short*)((char*)d_ws + szA);        // x1 bf16
        float* nA = (float*)((char*)d_ws + szA + szB);                     // ||x2[m]||
        float* nB = nA + M;                                                // ||x1[n]||
        prep_kernel<<<(M + 3) / 4, 256, 0, stream>>>(x2, Abf, nA, M, K);
        prep_kernel<<<(N + 3) / 4, 256, 0, stream>>>(x1, Bbf, nB, N, K);
        dim3 grid(N / BN, M / BM);
        gemm_cos_kernel<<<grid, 256, 0, stream>>>(Abf, Bbf, nA, nB, out, M, N, K);
    } else {
        long long total = (long long)M * N;
        int blocks = (int)((total + 255) / 256);
        naive_kernel<<<blocks, 256, 0, stream>>>(x1, x2, out, N, M, K);
    }
}